// Round 18
// baseline (158.529 us; speedup 1.0000x reference)
//
#include <hip/hip_runtime.h>

#define NN 50000
#define EE 800000
#define FF 128
#define OO 64
#define EPSF 1e-5f
#define SCB 196    // ceil(NN / 256)
#define GBLK 391   // ceil(NN / 128)
#define NB 256     // histogram chunks
#define EPB 3125   // EE / NB
#define NW 12500   // NN / 4 packed-count words
#define NSUB 3     // scatter sub-blocks per chunk
#define EPS3 1042  // ceil(EPB / NSUB)

typedef unsigned int uint;
typedef unsigned short ushort;
typedef unsigned char uchar;
typedef __attribute__((ext_vector_type(8))) short short8;  // 8 bf16 = 4 VGPR
typedef __attribute__((ext_vector_type(4))) float f32x4;
typedef __attribute__((ext_vector_type(4))) float floatx4;  // nontemporal-store safe

// ---- bf16 helpers (RTNE pack, cheap unpack) ----
__device__ __forceinline__ float bflo(uint v) { return __uint_as_float(v << 16); }
__device__ __forceinline__ float bfhi(uint v) { return __uint_as_float(v & 0xFFFF0000u); }
__device__ __forceinline__ uint f2bf(float f) {
  uint b = __float_as_uint(f);
  return (b + 0x7FFFu + ((b >> 16) & 1u)) >> 16;
}
__device__ __forceinline__ uint pack2(float x, float y) { return f2bf(x) | (f2bf(y) << 16); }

// ---- edge-index access: handles both int32 and int64 serialized layouts ----
__device__ __forceinline__ int eidx(const void* ei, long long pos, int f64) {
  if (f64) return (int)((const long long*)ei)[pos];
  return ((const int*)ei)[pos];
}

// per-wave int64-vs-int32 detect: odd 32-bit words all zero <=> int64.
__device__ __forceinline__ int detect_f64(const void* ei) {
  int lane = threadIdx.x & 63;
  int probe = ((const int*)ei)[2 * lane + 1];
  return __any(probe != 0) ? 0 : 1;
}

// ---- LDS-privatized degree histogram (no global atomics) ----
// Block b: LDS histogram of dst over its 3125 edges, 4 uchar counters per u32.
// LDS atomicAdd returns old word -> per-edge local rank (uchar).
// 1024 threads: 1 block/CU -> 50% occupancy (was 25% at 512).
__global__ __launch_bounds__(1024) void k_hist(const void* ei,
                                               uint* __restrict__ histW,
                                               uchar* __restrict__ lrank) {
  __shared__ uint lh[NW];  // 50 KB
  for (int w = threadIdx.x; w < NW; w += 1024) lh[w] = 0;
  __syncthreads();
  int f64 = detect_f64(ei);
  int b = blockIdx.x;
  for (int i = threadIdx.x; i < EPB; i += 1024) {
    int e = b * EPB + i;
    int d = eidx(ei, (long long)EE + e, f64);
    int sh = (d & 3) * 8;
    uint old = atomicAdd(&lh[d >> 2], 1u << sh);
    lrank[e] = (uchar)((old >> sh) & 255u);
  }
  __syncthreads();
  uint* dst = histW + (size_t)b * NW;
  for (int w = threadIdx.x; w < NW; w += 1024) dst[w] = lh[w];
}

// ---- column-wise exclusive prefix over hist[NB][NW] -> packed uchar boff,
// plus final per-node degree cnt (int). Coalesced across threads.
__global__ __launch_bounds__(256) void k_boff(const uint* __restrict__ histW,
                                              uint* __restrict__ boffW,
                                              int* __restrict__ cnt) {
  int w = blockIdx.x * 256 + threadIdx.x;
  if (w >= NW) return;
  uint s0 = 0, s1 = 0, s2 = 0, s3 = 0;
  for (int b = 0; b < NB; ++b) {
    uint hv = histW[(size_t)b * NW + w];
    boffW[(size_t)b * NW + w] = s0 | (s1 << 8) | (s2 << 16) | (s3 << 24);
    s0 += hv & 255u; s1 += (hv >> 8) & 255u;
    s2 += (hv >> 16) & 255u; s3 += (hv >> 24) & 255u;
  }
  int4 c4;
  c4.x = (int)s0; c4.y = (int)s1; c4.z = (int)s2; c4.w = (int)s3;
  ((int4*)cnt)[w] = c4;
}

// fused: dis = rsqrt(deg+1) + per-block partial sums for the scan
__global__ __launch_bounds__(256) void k_dis_part(const int* __restrict__ cnt,
                                                  float* __restrict__ dis,
                                                  int* __restrict__ bsum) {
  int i = blockIdx.x * 256 + threadIdx.x;
  int v = (i < NN) ? cnt[i] : 0;
  if (i < NN) dis[i] = rsqrtf((float)(v + 1));  // +1 self-loop, always > 0
  int s = v;
#pragma unroll
  for (int m = 1; m < 64; m <<= 1) s += __shfl_xor(s, m);
  __shared__ int ws[4];
  if ((threadIdx.x & 63) == 0) ws[threadIdx.x >> 6] = s;
  __syncthreads();
  if (threadIdx.x == 0) bsum[blockIdx.x] = ws[0] + ws[1] + ws[2] + ws[3];
}

// fused scan: every block redundantly scans the 196 bsums in LDS (cheap),
// derives its own block offset, then writes its rowptr slice.
__global__ __launch_bounds__(256) void k_scan_all(const int* __restrict__ cnt,
                                                  const int* __restrict__ bsum,
                                                  int* __restrict__ rowptr) {
  __shared__ int s[256];
  __shared__ int vv[256];
  __shared__ int wsum[4];
  int tid = threadIdx.x, blk = blockIdx.x;
  int v = (tid < SCB) ? bsum[tid] : 0;
  s[tid] = v;
  vv[tid] = v;
  __syncthreads();
  for (int off = 1; off < 256; off <<= 1) {
    int t = (tid >= off) ? s[tid - off] : 0;
    __syncthreads();
    s[tid] += t;
    __syncthreads();
  }
  if (blk == 0 && tid == 255) rowptr[NN] = s[255];  // total = EE
  int boff = s[blk] - vv[blk];                      // exclusive prefix of this block
  int i = blk * 256 + tid;
  int c = (i < NN) ? cnt[i] : 0;
  int lane = tid & 63, wid = tid >> 6;
  int inc = c;
#pragma unroll
  for (int off = 1; off < 64; off <<= 1) {
    int t = __shfl_up(inc, off);
    if (lane >= off) inc += t;
  }
  if (lane == 63) wsum[wid] = inc;
  __syncthreads();
  int wadd = 0;
  for (int wj = 0; wj < wid; ++wj) wadd += wsum[wj];
  int exc = inc - c + wadd + boff;
  if (i < NN) rowptr[i] = exc;
}

// ---- fused rank+scatter, occupancy-sized: NSUB blocks per chunk, each stages
// the chunk's 50 KB boff slice (coalesced) and scatters 1/NSUB of its edges.
// 768 blocks x 512 threads, 3 blocks/CU (LDS-limited) = 75% occupancy.
__global__ __launch_bounds__(512) void k_scatter2(const void* ei,
                                                  const uint* __restrict__ boffW,
                                                  const uchar* __restrict__ lrank,
                                                  const int* __restrict__ rowptr,
                                                  const float* __restrict__ dis,
                                                  int2* __restrict__ cw) {
  __shared__ uint sb[NW];  // 50 KB
  int b = blockIdx.x / NSUB;
  int sub = blockIdx.x % NSUB;
  const uint* src = boffW + (size_t)b * NW;
  for (int w = threadIdx.x; w < NW; w += 512) sb[w] = src[w];
  __syncthreads();
  int f64 = detect_f64(ei);
  int e0 = b * EPB;
  int i0 = sub * EPS3;
  int i1 = min(EPB, i0 + EPS3);
  for (int i = i0 + threadIdx.x; i < i1; i += 512) {
    int e = e0 + i;
    int rk = (int)lrank[e];  // coalesced, issue early
    int s = eidx(ei, e, f64);
    int d = eidx(ei, (long long)EE + e, f64);
    uint bw = sb[d >> 2];
    int bo = (int)((bw >> ((d & 3) * 8)) & 255u);
    int p = rowptr[d] + bo + rk;
    int2 v;
    v.x = s;
    v.y = __float_as_int(dis[s] * dis[d]);
    cw[p] = v;
  }
}

// swizzled LDS index for Wt[c][k] (ushort units): c*128 + (k ^ ((c&7)<<3))
__device__ __forceinline__ int wt_idx(int c, int k) {
  return c * 128 + (k ^ ((c & 7) << 3));
}

// ---- MFMA GEMM 1 (standalone): T(bf16)[N][128] = X(f32) @ W1(f32->bf16) ----
__global__ __launch_bounds__(256) void k_gemm1(const float* __restrict__ X,
                                               const float* __restrict__ W,
                                               ushort* __restrict__ T) {
  __shared__ ushort Wt[FF * FF];  // 32 KB
  for (int i = threadIdx.x; i < FF * FF; i += 256) {
    int k = i >> 7, c = i & 127;
    Wt[wt_idx(c, k)] = (ushort)f2bf(W[i]);
  }
  __syncthreads();
  int l = threadIdx.x & 63, wv = threadIdx.x >> 6;
  int rbase = blockIdx.x * 128 + wv * 32;
  int lr = l & 15, lk = (l >> 4) << 3;
  f32x4 acc[2][8] = {};
#pragma unroll
  for (int kb = 0; kb < 4; ++kb) {
    int kk = kb * 32 + lk;
    short8 a[2];
#pragma unroll
    for (int rt = 0; rt < 2; ++rt) {
      int row = min(rbase + rt * 16 + lr, NN - 1);
      const float4* ap = (const float4*)(X + (size_t)row * FF + kk);
      float4 x0 = ap[0], x1 = ap[1];
      a[rt][0] = (short)f2bf(x0.x); a[rt][1] = (short)f2bf(x0.y);
      a[rt][2] = (short)f2bf(x0.z); a[rt][3] = (short)f2bf(x0.w);
      a[rt][4] = (short)f2bf(x1.x); a[rt][5] = (short)f2bf(x1.y);
      a[rt][6] = (short)f2bf(x1.z); a[rt][7] = (short)f2bf(x1.w);
    }
#pragma unroll
    for (int ct = 0; ct < 8; ++ct) {
      int c = ct * 16 + lr;
      short8 b = *(const short8*)&Wt[wt_idx(c, kk)];
      acc[0][ct] = __builtin_amdgcn_mfma_f32_16x16x32_bf16(a[0], b, acc[0][ct], 0, 0, 0);
      acc[1][ct] = __builtin_amdgcn_mfma_f32_16x16x32_bf16(a[1], b, acc[1][ct], 0, 0, 0);
    }
  }
  int rl = (l >> 4) * 4;  // C/D: col = lane&15, row = (lane>>4)*4 + reg
#pragma unroll
  for (int rt = 0; rt < 2; ++rt)
#pragma unroll
    for (int reg = 0; reg < 4; ++reg) {
      int row = rbase + rt * 16 + rl + reg;
      if (row < NN) {
#pragma unroll
        for (int ct = 0; ct < 8; ++ct)
          T[(size_t)row * FF + ct * 16 + lr] = (ushort)f2bf(acc[rt][ct][reg]);
      }
    }
}

// ---- MFMA GEMM: hw(bf16)[N][128] = h(bf16) @ [Wmu|Wlv] (no bias here) ----
__global__ __launch_bounds__(256) void k_gemmHW(const ushort* __restrict__ A,
                                                const float* __restrict__ Wmu,
                                                const float* __restrict__ Wlv,
                                                ushort* __restrict__ T) {
  __shared__ ushort Wt[FF * FF];
  for (int i = threadIdx.x; i < FF * FF; i += 256) {
    int k = i >> 7, c = i & 127;
    float v = (c < OO) ? Wmu[k * OO + c] : Wlv[k * OO + (c - OO)];
    Wt[wt_idx(c, k)] = (ushort)f2bf(v);
  }
  __syncthreads();
  int l = threadIdx.x & 63, wv = threadIdx.x >> 6;
  int rbase = blockIdx.x * 128 + wv * 32;
  int lr = l & 15, lk = (l >> 4) << 3;
  f32x4 acc[2][8] = {};
#pragma unroll
  for (int kb = 0; kb < 4; ++kb) {
    int kk = kb * 32 + lk;
    short8 a[2];
#pragma unroll
    for (int rt = 0; rt < 2; ++rt) {
      int row = min(rbase + rt * 16 + lr, NN - 1);
      a[rt] = *(const short8*)(A + (size_t)row * FF + kk);
    }
#pragma unroll
    for (int ct = 0; ct < 8; ++ct) {
      int c = ct * 16 + lr;
      short8 b = *(const short8*)&Wt[wt_idx(c, kk)];
      acc[0][ct] = __builtin_amdgcn_mfma_f32_16x16x32_bf16(a[0], b, acc[0][ct], 0, 0, 0);
      acc[1][ct] = __builtin_amdgcn_mfma_f32_16x16x32_bf16(a[1], b, acc[1][ct], 0, 0, 0);
    }
  }
  int rl = (l >> 4) * 4;
#pragma unroll
  for (int rt = 0; rt < 2; ++rt)
#pragma unroll
    for (int reg = 0; reg < 4; ++reg) {
      int row = rbase + rt * 16 + rl + reg;
      if (row < NN) {
#pragma unroll
        for (int ct = 0; ct < 8; ++ct)
          T[(size_t)row * FF + ct * 16 + lr] = (ushort)f2bf(acc[rt][ct][reg]);
      }
    }
}

// gather conv1: one wave per node, wide rows (4 edges / VMEM instr), fused
// bias+ReLU+LayerNorm epilogue, bf16 out (cached: gemmHW re-reads h).
__global__ __launch_bounds__(256) void k_gather_ln(const int* __restrict__ rowptr,
                                                   const int2* __restrict__ cw,
                                                   const float* __restrict__ dis,
                                                   const ushort* __restrict__ feat,
                                                   const float* __restrict__ b1,
                                                   const float* __restrict__ gamma,
                                                   const float* __restrict__ beta,
                                                   ushort* __restrict__ outp) {
  int node = blockIdx.x * 4 + (threadIdx.x >> 6);
  if (node >= NN) return;
  int l = threadIdx.x & 63;
  int g = l >> 4;    // edge slot within wave
  int c16 = l & 15;  // 16-byte column chunk

  float di = dis[node];
  uint4 vSelf = ((const uint4*)(feat + ((size_t)node << 7)))[c16];

  float acc[8] = {};
  int e0 = rowptr[node], nE = rowptr[node + 1] - e0;
  int base = 0;
  for (; base + 8 <= nE; base += 8) {
    int2 cA = cw[e0 + base + g];
    int2 cB = cw[e0 + base + 4 + g];
    uint4 vA = ((const uint4*)(feat + ((size_t)cA.x << 7)))[c16];
    uint4 vB = ((const uint4*)(feat + ((size_t)cB.x << 7)))[c16];
    float wA = __int_as_float(cA.y), wB = __int_as_float(cB.y);
    acc[0] = fmaf(wA, bflo(vA.x), acc[0]); acc[1] = fmaf(wA, bfhi(vA.x), acc[1]);
    acc[2] = fmaf(wA, bflo(vA.y), acc[2]); acc[3] = fmaf(wA, bfhi(vA.y), acc[3]);
    acc[4] = fmaf(wA, bflo(vA.z), acc[4]); acc[5] = fmaf(wA, bfhi(vA.z), acc[5]);
    acc[6] = fmaf(wA, bflo(vA.w), acc[6]); acc[7] = fmaf(wA, bfhi(vA.w), acc[7]);
    acc[0] = fmaf(wB, bflo(vB.x), acc[0]); acc[1] = fmaf(wB, bfhi(vB.x), acc[1]);
    acc[2] = fmaf(wB, bflo(vB.y), acc[2]); acc[3] = fmaf(wB, bfhi(vB.y), acc[3]);
    acc[4] = fmaf(wB, bflo(vB.z), acc[4]); acc[5] = fmaf(wB, bfhi(vB.z), acc[5]);
    acc[6] = fmaf(wB, bflo(vB.w), acc[6]); acc[7] = fmaf(wB, bfhi(vB.w), acc[7]);
  }
#pragma unroll
  for (int t = 0; t < 2; ++t) {
    int idx = base + t * 4 + g;
    if (idx < nE) {
      int2 c0 = cw[e0 + idx];
      uint4 v = ((const uint4*)(feat + ((size_t)c0.x << 7)))[c16];
      float w0 = __int_as_float(c0.y);
      acc[0] = fmaf(w0, bflo(v.x), acc[0]); acc[1] = fmaf(w0, bfhi(v.x), acc[1]);
      acc[2] = fmaf(w0, bflo(v.y), acc[2]); acc[3] = fmaf(w0, bfhi(v.y), acc[3]);
      acc[4] = fmaf(w0, bflo(v.z), acc[4]); acc[5] = fmaf(w0, bfhi(v.z), acc[5]);
      acc[6] = fmaf(w0, bflo(v.w), acc[6]); acc[7] = fmaf(w0, bfhi(v.w), acc[7]);
    }
  }
#pragma unroll
  for (int j = 0; j < 8; ++j) {
    acc[j] += __shfl_xor(acc[j], 16);
    acc[j] += __shfl_xor(acc[j], 32);
  }
  {
    float sw = di * di;
    acc[0] = fmaf(sw, bflo(vSelf.x), acc[0]); acc[1] = fmaf(sw, bfhi(vSelf.x), acc[1]);
    acc[2] = fmaf(sw, bflo(vSelf.y), acc[2]); acc[3] = fmaf(sw, bfhi(vSelf.y), acc[3]);
    acc[4] = fmaf(sw, bflo(vSelf.z), acc[4]); acc[5] = fmaf(sw, bfhi(vSelf.z), acc[5]);
    acc[6] = fmaf(sw, bflo(vSelf.w), acc[6]); acc[7] = fmaf(sw, bfhi(vSelf.w), acc[7]);
  }
  int cOff = c16 * 8;
  float4 ba = *(const float4*)&b1[cOff];
  float4 bb = *(const float4*)&b1[cOff + 4];
  float a[8];
  a[0] = fmaxf(acc[0] + ba.x, 0.f); a[1] = fmaxf(acc[1] + ba.y, 0.f);
  a[2] = fmaxf(acc[2] + ba.z, 0.f); a[3] = fmaxf(acc[3] + ba.w, 0.f);
  a[4] = fmaxf(acc[4] + bb.x, 0.f); a[5] = fmaxf(acc[5] + bb.y, 0.f);
  a[6] = fmaxf(acc[6] + bb.z, 0.f); a[7] = fmaxf(acc[7] + bb.w, 0.f);
  float s = 0.f, sq = 0.f;
#pragma unroll
  for (int j = 0; j < 8; ++j) { s += a[j]; sq += a[j] * a[j]; }
#pragma unroll
  for (int m = 1; m < 16; m <<= 1) {
    s += __shfl_xor(s, m);
    sq += __shfl_xor(sq, m);
  }
  float mean = s * (1.f / 128.f);
  float var = sq * (1.f / 128.f) - mean * mean;
  float rstd = rsqrtf(var + EPSF);
  float4 ga = *(const float4*)&gamma[cOff];
  float4 gb = *(const float4*)&gamma[cOff + 4];
  float4 ea = *(const float4*)&beta[cOff];
  float4 eb = *(const float4*)&beta[cOff + 4];
  float o[8];
  o[0] = (a[0] - mean) * rstd * ga.x + ea.x; o[1] = (a[1] - mean) * rstd * ga.y + ea.y;
  o[2] = (a[2] - mean) * rstd * ga.z + ea.z; o[3] = (a[3] - mean) * rstd * ga.w + ea.w;
  o[4] = (a[4] - mean) * rstd * gb.x + eb.x; o[5] = (a[5] - mean) * rstd * gb.y + eb.y;
  o[6] = (a[6] - mean) * rstd * gb.z + eb.z; o[7] = (a[7] - mean) * rstd * gb.w + eb.w;
  if (g == 0) {
    uint4 p;
    p.x = pack2(o[0], o[1]); p.y = pack2(o[2], o[3]);
    p.z = pack2(o[4], o[5]); p.w = pack2(o[6], o[7]);
    ((uint4*)(outp + ((size_t)node << 7)))[c16] = p;
  }
}

// gather conv2+3 over hw, writes f32 [mu|logvar] directly with bias (nontemporal)
__global__ __launch_bounds__(256) void k_gather_out(const int* __restrict__ rowptr,
                                                    const int2* __restrict__ cw,
                                                    const float* __restrict__ dis,
                                                    const ushort* __restrict__ feat,
                                                    const float* __restrict__ bmu,
                                                    const float* __restrict__ blv,
                                                    float* __restrict__ out) {
  int node = blockIdx.x * 4 + (threadIdx.x >> 6);
  if (node >= NN) return;
  int l = threadIdx.x & 63;
  int g = l >> 4;
  int c16 = l & 15;

  float di = dis[node];
  uint4 vSelf = ((const uint4*)(feat + ((size_t)node << 7)))[c16];

  float acc[8] = {};
  int e0 = rowptr[node], nE = rowptr[node + 1] - e0;
  int base = 0;
  for (; base + 8 <= nE; base += 8) {
    int2 cA = cw[e0 + base + g];
    int2 cB = cw[e0 + base + 4 + g];
    uint4 vA = ((const uint4*)(feat + ((size_t)cA.x << 7)))[c16];
    uint4 vB = ((const uint4*)(feat + ((size_t)cB.x << 7)))[c16];
    float wA = __int_as_float(cA.y), wB = __int_as_float(cB.y);
    acc[0] = fmaf(wA, bflo(vA.x), acc[0]); acc[1] = fmaf(wA, bfhi(vA.x), acc[1]);
    acc[2] = fmaf(wA, bflo(vA.y), acc[2]); acc[3] = fmaf(wA, bfhi(vA.y), acc[3]);
    acc[4] = fmaf(wA, bflo(vA.z), acc[4]); acc[5] = fmaf(wA, bfhi(vA.z), acc[5]);
    acc[6] = fmaf(wA, bflo(vA.w), acc[6]); acc[7] = fmaf(wA, bfhi(vA.w), acc[7]);
    acc[0] = fmaf(wB, bflo(vB.x), acc[0]); acc[1] = fmaf(wB, bfhi(vB.x), acc[1]);
    acc[2] = fmaf(wB, bflo(vB.y), acc[2]); acc[3] = fmaf(wB, bfhi(vB.y), acc[3]);
    acc[4] = fmaf(wB, bflo(vB.z), acc[4]); acc[5] = fmaf(wB, bfhi(vB.z), acc[5]);
    acc[6] = fmaf(wB, bflo(vB.w), acc[6]); acc[7] = fmaf(wB, bfhi(vB.w), acc[7]);
  }
#pragma unroll
  for (int t = 0; t < 2; ++t) {
    int idx = base + t * 4 + g;
    if (idx < nE) {
      int2 c0 = cw[e0 + idx];
      uint4 v = ((const uint4*)(feat + ((size_t)c0.x << 7)))[c16];
      float w0 = __int_as_float(c0.y);
      acc[0] = fmaf(w0, bflo(v.x), acc[0]); acc[1] = fmaf(w0, bfhi(v.x), acc[1]);
      acc[2] = fmaf(w0, bflo(v.y), acc[2]); acc[3] = fmaf(w0, bfhi(v.y), acc[3]);
      acc[4] = fmaf(w0, bflo(v.z), acc[4]); acc[5] = fmaf(w0, bfhi(v.z), acc[5]);
      acc[6] = fmaf(w0, bflo(v.w), acc[6]); acc[7] = fmaf(w0, bfhi(v.w), acc[7]);
    }
  }
#pragma unroll
  for (int j = 0; j < 8; ++j) {
    acc[j] += __shfl_xor(acc[j], 16);
    acc[j] += __shfl_xor(acc[j], 32);
  }
  {
    float sw = di * di;
    acc[0] = fmaf(sw, bflo(vSelf.x), acc[0]); acc[1] = fmaf(sw, bfhi(vSelf.x), acc[1]);
    acc[2] = fmaf(sw, bflo(vSelf.y), acc[2]); acc[3] = fmaf(sw, bfhi(vSelf.y), acc[3]);
    acc[4] = fmaf(sw, bflo(vSelf.z), acc[4]); acc[5] = fmaf(sw, bfhi(vSelf.z), acc[5]);
    acc[6] = fmaf(sw, bflo(vSelf.w), acc[6]); acc[7] = fmaf(sw, bfhi(vSelf.w), acc[7]);
  }
  if (g == 0) {
    // feats c16*8..+8 of [mu(64) | logvar(64)]
    const float* bsrc = (c16 < 8) ? (bmu + c16 * 8) : (blv + (c16 - 8) * 8);
    float* osrc = (c16 < 8) ? (out + (size_t)node * OO + c16 * 8)
                            : (out + (size_t)NN * OO + (size_t)node * OO + (c16 - 8) * 8);
    float4 b0 = *(const float4*)bsrc;
    float4 b1 = *(const float4*)(bsrc + 4);
    floatx4 o0 = { acc[0] + b0.x, acc[1] + b0.y, acc[2] + b0.z, acc[3] + b0.w };
    floatx4 o1 = { acc[4] + b1.x, acc[5] + b1.y, acc[6] + b1.z, acc[7] + b1.w };
    __builtin_nontemporal_store(o0, (floatx4*)osrc);
    __builtin_nontemporal_store(o1, (floatx4*)(osrc + 4));
  }
}

extern "C" void kernel_launch(void* const* d_in, const int* in_sizes, int n_in,
                              void* d_out, int out_size, void* d_ws, size_t ws_size,
                              hipStream_t stream) {
  const float* x     = (const float*)d_in[0];
  const void*  ei    = d_in[1];
  const float* W1    = (const float*)d_in[2];
  const float* b1    = (const float*)d_in[3];
  const float* gamma = (const float*)d_in[4];
  const float* beta  = (const float*)d_in[5];
  const float* Wmu   = (const float*)d_in[6];
  const float* bmu   = (const float*)d_in[7];
  const float* Wlv   = (const float*)d_in[8];
  const float* blv   = (const float*)d_in[9];
  float* out = (float*)d_out;

  // workspace (4B words), ~72 MB:
  // [rowptr N+16][dis N][bsum 256][cnt N][histW NB*NW][boffW NB*NW]
  // [lrank E bytes][cw int2 E][t bf16][h bf16][hw bf16]
  int*   rowptr = (int*)d_ws;
  float* dis    = (float*)(rowptr + (NN + 16));
  int*   bsum   = (int*)(dis + NN);
  int*   cnt    = bsum + 256;                       // 16B-aligned (offset%4==0)
  uint*  histW  = (uint*)(cnt + NN);
  uint*  boffW  = histW + (size_t)NB * NW;
  uchar* lrank  = (uchar*)(boffW + (size_t)NB * NW);
  size_t off32  = (size_t)(NN + 16) + NN + 256 + NN + 2 * (size_t)NB * NW + EE / 4;
  off32 = (off32 + 63) & ~(size_t)63;
  int2*  cw     = (int2*)((int*)d_ws + off32);
  ushort* t  = (ushort*)(cw + EE);
  ushort* h  = t + (size_t)NN * FF;
  ushort* hw = h + (size_t)NN * FF;

  k_gemm1<<<GBLK, 256, 0, stream>>>(x, W1, t);
  k_hist<<<NB, 1024, 0, stream>>>(ei, histW, lrank);
  k_boff<<<(NW + 255) / 256, 256, 0, stream>>>(histW, boffW, cnt);
  k_dis_part<<<SCB, 256, 0, stream>>>(cnt, dis, bsum);
  k_scan_all<<<SCB, 256, 0, stream>>>(cnt, bsum, rowptr);
  k_scatter2<<<NB * NSUB, 512, 0, stream>>>(ei, boffW, lrank, rowptr, dis, cw);

  k_gather_ln<<<(NN + 3) / 4, 256, 0, stream>>>(rowptr, cw, dis, t, b1, gamma, beta, h);
  k_gemmHW<<<GBLK, 256, 0, stream>>>(h, Wmu, Wlv, hw);
  k_gather_out<<<(NN + 3) / 4, 256, 0, stream>>>(rowptr, cw, dis, hw, bmu, blv, out);
}

// Round 19
// 148.329 us; speedup vs baseline: 1.0688x; 1.0688x over previous
//
#include <hip/hip_runtime.h>

#define NN 50000
#define EE 800000
#define FF 128
#define OO 64
#define EPSF 1e-5f
#define SCB 196    // ceil(NN / 256)
#define GBLK 391   // ceil(NN / 128)
#define NB 256     // histogram / scatter chunks
#define EPB 3125   // EE / NB
#define NW 12500   // NN / 4 packed-count words

typedef unsigned int uint;
typedef unsigned short ushort;
typedef unsigned char uchar;
typedef __attribute__((ext_vector_type(8))) short short8;  // 8 bf16 = 4 VGPR
typedef __attribute__((ext_vector_type(4))) float f32x4;
typedef __attribute__((ext_vector_type(4))) float floatx4;  // nontemporal-store safe

// ---- bf16 helpers (RTNE pack, cheap unpack) ----
__device__ __forceinline__ float bflo(uint v) { return __uint_as_float(v << 16); }
__device__ __forceinline__ float bfhi(uint v) { return __uint_as_float(v & 0xFFFF0000u); }
__device__ __forceinline__ uint f2bf(float f) {
  uint b = __float_as_uint(f);
  return (b + 0x7FFFu + ((b >> 16) & 1u)) >> 16;
}
__device__ __forceinline__ uint pack2(float x, float y) { return f2bf(x) | (f2bf(y) << 16); }

// ---- edge-index access: handles both int32 and int64 serialized layouts ----
__device__ __forceinline__ int eidx(const void* ei, long long pos, int f64) {
  if (f64) return (int)((const long long*)ei)[pos];
  return ((const int*)ei)[pos];
}

// per-wave int64-vs-int32 detect: odd 32-bit words all zero <=> int64.
__device__ __forceinline__ int detect_f64(const void* ei) {
  int lane = threadIdx.x & 63;
  int probe = ((const int*)ei)[2 * lane + 1];
  return __any(probe != 0) ? 0 : 1;
}

// ---- LDS-privatized degree histogram (no global atomics) ----
// Block b: LDS histogram of dst over its 3125 edges, 4 uchar counters per u32.
// LDS atomicAdd returns old word -> per-edge local rank (uchar).
__global__ __launch_bounds__(512) void k_hist(const void* ei,
                                              uint* __restrict__ histW,
                                              uchar* __restrict__ lrank) {
  __shared__ uint lh[NW];  // 50 KB
  for (int w = threadIdx.x; w < NW; w += 512) lh[w] = 0;
  __syncthreads();
  int f64 = detect_f64(ei);
  int b = blockIdx.x;
  for (int i = threadIdx.x; i < EPB; i += 512) {
    int e = b * EPB + i;
    int d = eidx(ei, (long long)EE + e, f64);
    int sh = (d & 3) * 8;
    uint old = atomicAdd(&lh[d >> 2], 1u << sh);
    lrank[e] = (uchar)((old >> sh) & 255u);
  }
  __syncthreads();
  uint* dst = histW + (size_t)b * NW;
  for (int w = threadIdx.x; w < NW; w += 512) dst[w] = lh[w];
}

// ---- column-wise exclusive prefix over hist[NB][NW] -> packed uchar boff,
// plus (fused) per-node degree cnt, dis = rsqrt(deg+1), and per-256-node bsum
// for the scan (wave j of block b covers exactly bsum entry 4b+j).
__global__ __launch_bounds__(256) void k_boff(const uint* __restrict__ histW,
                                              uint* __restrict__ boffW,
                                              int* __restrict__ cnt,
                                              float* __restrict__ dis,
                                              int* __restrict__ bsum) {
  int w = blockIdx.x * 256 + threadIdx.x;
  uint s0 = 0, s1 = 0, s2 = 0, s3 = 0;
  if (w < NW) {
    for (int b = 0; b < NB; ++b) {
      uint hv = histW[(size_t)b * NW + w];
      boffW[(size_t)b * NW + w] = s0 | (s1 << 8) | (s2 << 16) | (s3 << 24);
      s0 += hv & 255u; s1 += (hv >> 8) & 255u;
      s2 += (hv >> 16) & 255u; s3 += (hv >> 24) & 255u;
    }
    int4 c4;
    c4.x = (int)s0; c4.y = (int)s1; c4.z = (int)s2; c4.w = (int)s3;
    ((int4*)cnt)[w] = c4;
    float4 d4;
    d4.x = rsqrtf((float)(s0 + 1)); d4.y = rsqrtf((float)(s1 + 1));
    d4.z = rsqrtf((float)(s2 + 1)); d4.w = rsqrtf((float)(s3 + 1));
    ((float4*)dis)[w] = d4;
  }
  int ss = (int)(s0 + s1 + s2 + s3);
#pragma unroll
  for (int m = 1; m < 64; m <<= 1) ss += __shfl_xor(ss, m);
  if ((threadIdx.x & 63) == 0) bsum[blockIdx.x * 4 + (threadIdx.x >> 6)] = ss;
}

// fused scan: every block redundantly scans the 196 bsums in LDS (cheap),
// derives its own block offset, then writes its rowptr slice.
__global__ __launch_bounds__(256) void k_scan_all(const int* __restrict__ cnt,
                                                  const int* __restrict__ bsum,
                                                  int* __restrict__ rowptr) {
  __shared__ int s[256];
  __shared__ int vv[256];
  __shared__ int wsum[4];
  int tid = threadIdx.x, blk = blockIdx.x;
  int v = (tid < SCB) ? bsum[tid] : 0;
  s[tid] = v;
  vv[tid] = v;
  __syncthreads();
  for (int off = 1; off < 256; off <<= 1) {
    int t = (tid >= off) ? s[tid - off] : 0;
    __syncthreads();
    s[tid] += t;
    __syncthreads();
  }
  if (blk == 0 && tid == 255) rowptr[NN] = s[255];  // total = EE
  int boff = s[blk] - vv[blk];                      // exclusive prefix of this block
  int i = blk * 256 + tid;
  int c = (i < NN) ? cnt[i] : 0;
  int lane = tid & 63, wid = tid >> 6;
  int inc = c;
#pragma unroll
  for (int off = 1; off < 64; off <<= 1) {
    int t = __shfl_up(inc, off);
    if (lane >= off) inc += t;
  }
  if (lane == 63) wsum[wid] = inc;
  __syncthreads();
  int wadd = 0;
  for (int wj = 0; wj < wid; ++wj) wadd += wsum[wj];
  int exc = inc - c + wadd + boff;
  if (i < NN) rowptr[i] = exc;
}

// swizzled LDS index for Wt[c][k] (ushort units): c*128 + (k ^ ((c&7)<<3))
__device__ __forceinline__ int wt_idx(int c, int k) {
  return c * 128 + (k ^ ((c & 7) << 3));
}

// ---- DUAL-ROLE (best-measured R15 config): blocks [0,GBLK) = MFMA GEMM1;
// blocks [GBLK,GBLK+NB) = CSR scatter, one 3125-edge chunk per block with the
// chunk's 50 KB boff slice staged in LDS (coalesced). GEMM dispatches first;
// scatter hides partially under it.
__global__ __launch_bounds__(256) void k_scatter_gemm1(
    const void* ei, const float* __restrict__ dis,
    const int* __restrict__ rowptr, const uint* __restrict__ boffW,
    const uchar* __restrict__ lrank, int2* __restrict__ cw,
    const float* __restrict__ X, const float* __restrict__ W,
    ushort* __restrict__ T) {
  __shared__ uint shmem[NW];  // 50 KB; 3 blocks/CU
  if (blockIdx.x >= GBLK) {
    // ---- scatter role ----
    int sb = blockIdx.x - GBLK;  // chunk = hist block index
    const uint* bsrc = boffW + (size_t)sb * NW;
    for (int w = threadIdx.x; w < NW; w += 256) shmem[w] = bsrc[w];
    __syncthreads();
    int f64 = detect_f64(ei);
    int e0 = sb * EPB;
    for (int i = threadIdx.x; i < EPB; i += 256) {
      int e = e0 + i;
      int s = eidx(ei, e, f64);
      int d = eidx(ei, (long long)EE + e, f64);
      uint bw = shmem[d >> 2];
      int bo = (int)((bw >> ((d & 3) * 8)) & 255u);
      int p = rowptr[d] + bo + (int)lrank[e];
      int2 v;
      v.x = s;
      v.y = __float_as_int(dis[s] * dis[d]);
      cw[p] = v;
    }
    return;
  }
  // ---- GEMM1 role: T(bf16)[N][128] = X(f32) @ W1(f32->bf16) ----
  ushort* Wt = (ushort*)shmem;
  for (int i = threadIdx.x; i < FF * FF; i += 256) {
    int k = i >> 7, c = i & 127;
    Wt[wt_idx(c, k)] = (ushort)f2bf(W[i]);
  }
  __syncthreads();
  int l = threadIdx.x & 63, wv = threadIdx.x >> 6;
  int rbase = blockIdx.x * 128 + wv * 32;
  int lr = l & 15, lk = (l >> 4) << 3;
  f32x4 acc[2][8] = {};
#pragma unroll
  for (int kb = 0; kb < 4; ++kb) {
    int kk = kb * 32 + lk;
    short8 a[2];
#pragma unroll
    for (int rt = 0; rt < 2; ++rt) {
      int row = min(rbase + rt * 16 + lr, NN - 1);
      const float4* ap = (const float4*)(X + (size_t)row * FF + kk);
      float4 x0 = ap[0], x1 = ap[1];
      a[rt][0] = (short)f2bf(x0.x); a[rt][1] = (short)f2bf(x0.y);
      a[rt][2] = (short)f2bf(x0.z); a[rt][3] = (short)f2bf(x0.w);
      a[rt][4] = (short)f2bf(x1.x); a[rt][5] = (short)f2bf(x1.y);
      a[rt][6] = (short)f2bf(x1.z); a[rt][7] = (short)f2bf(x1.w);
    }
#pragma unroll
    for (int ct = 0; ct < 8; ++ct) {
      int c = ct * 16 + lr;
      short8 b = *(const short8*)&Wt[wt_idx(c, kk)];
      acc[0][ct] = __builtin_amdgcn_mfma_f32_16x16x32_bf16(a[0], b, acc[0][ct], 0, 0, 0);
      acc[1][ct] = __builtin_amdgcn_mfma_f32_16x16x32_bf16(a[1], b, acc[1][ct], 0, 0, 0);
    }
  }
  int rl = (l >> 4) * 4;  // C/D: col = lane&15, row = (lane>>4)*4 + reg
#pragma unroll
  for (int rt = 0; rt < 2; ++rt)
#pragma unroll
    for (int reg = 0; reg < 4; ++reg) {
      int row = rbase + rt * 16 + rl + reg;
      if (row < NN) {
#pragma unroll
        for (int ct = 0; ct < 8; ++ct)
          T[(size_t)row * FF + ct * 16 + lr] = (ushort)f2bf(acc[rt][ct][reg]);
      }
    }
}

// ---- MFMA GEMM: hw(bf16)[N][128] = h(bf16) @ [Wmu|Wlv] (no bias here) ----
__global__ __launch_bounds__(256) void k_gemmHW(const ushort* __restrict__ A,
                                                const float* __restrict__ Wmu,
                                                const float* __restrict__ Wlv,
                                                ushort* __restrict__ T) {
  __shared__ ushort Wt[FF * FF];
  for (int i = threadIdx.x; i < FF * FF; i += 256) {
    int k = i >> 7, c = i & 127;
    float v = (c < OO) ? Wmu[k * OO + c] : Wlv[k * OO + (c - OO)];
    Wt[wt_idx(c, k)] = (ushort)f2bf(v);
  }
  __syncthreads();
  int l = threadIdx.x & 63, wv = threadIdx.x >> 6;
  int rbase = blockIdx.x * 128 + wv * 32;
  int lr = l & 15, lk = (l >> 4) << 3;
  f32x4 acc[2][8] = {};
#pragma unroll
  for (int kb = 0; kb < 4; ++kb) {
    int kk = kb * 32 + lk;
    short8 a[2];
#pragma unroll
    for (int rt = 0; rt < 2; ++rt) {
      int row = min(rbase + rt * 16 + lr, NN - 1);
      a[rt] = *(const short8*)(A + (size_t)row * FF + kk);
    }
#pragma unroll
    for (int ct = 0; ct < 8; ++ct) {
      int c = ct * 16 + lr;
      short8 b = *(const short8*)&Wt[wt_idx(c, kk)];
      acc[0][ct] = __builtin_amdgcn_mfma_f32_16x16x32_bf16(a[0], b, acc[0][ct], 0, 0, 0);
      acc[1][ct] = __builtin_amdgcn_mfma_f32_16x16x32_bf16(a[1], b, acc[1][ct], 0, 0, 0);
    }
  }
  int rl = (l >> 4) * 4;
#pragma unroll
  for (int rt = 0; rt < 2; ++rt)
#pragma unroll
    for (int reg = 0; reg < 4; ++reg) {
      int row = rbase + rt * 16 + rl + reg;
      if (row < NN) {
#pragma unroll
        for (int ct = 0; ct < 8; ++ct)
          T[(size_t)row * FF + ct * 16 + lr] = (ushort)f2bf(acc[rt][ct][reg]);
      }
    }
}

// gather conv1: one wave per node, wide rows (4 edges / VMEM instr), fused
// bias+ReLU+LayerNorm epilogue, bf16 out (cached: gemmHW re-reads h).
__global__ __launch_bounds__(256) void k_gather_ln(const int* __restrict__ rowptr,
                                                   const int2* __restrict__ cw,
                                                   const float* __restrict__ dis,
                                                   const ushort* __restrict__ feat,
                                                   const float* __restrict__ b1,
                                                   const float* __restrict__ gamma,
                                                   const float* __restrict__ beta,
                                                   ushort* __restrict__ outp) {
  int node = blockIdx.x * 4 + (threadIdx.x >> 6);
  if (node >= NN) return;
  int l = threadIdx.x & 63;
  int g = l >> 4;    // edge slot within wave
  int c16 = l & 15;  // 16-byte column chunk

  float di = dis[node];
  uint4 vSelf = ((const uint4*)(feat + ((size_t)node << 7)))[c16];

  float acc[8] = {};
  int e0 = rowptr[node], nE = rowptr[node + 1] - e0;
  int base = 0;
  for (; base + 8 <= nE; base += 8) {
    int2 cA = cw[e0 + base + g];
    int2 cB = cw[e0 + base + 4 + g];
    uint4 vA = ((const uint4*)(feat + ((size_t)cA.x << 7)))[c16];
    uint4 vB = ((const uint4*)(feat + ((size_t)cB.x << 7)))[c16];
    float wA = __int_as_float(cA.y), wB = __int_as_float(cB.y);
    acc[0] = fmaf(wA, bflo(vA.x), acc[0]); acc[1] = fmaf(wA, bfhi(vA.x), acc[1]);
    acc[2] = fmaf(wA, bflo(vA.y), acc[2]); acc[3] = fmaf(wA, bfhi(vA.y), acc[3]);
    acc[4] = fmaf(wA, bflo(vA.z), acc[4]); acc[5] = fmaf(wA, bfhi(vA.z), acc[5]);
    acc[6] = fmaf(wA, bflo(vA.w), acc[6]); acc[7] = fmaf(wA, bfhi(vA.w), acc[7]);
    acc[0] = fmaf(wB, bflo(vB.x), acc[0]); acc[1] = fmaf(wB, bfhi(vB.x), acc[1]);
    acc[2] = fmaf(wB, bflo(vB.y), acc[2]); acc[3] = fmaf(wB, bfhi(vB.y), acc[3]);
    acc[4] = fmaf(wB, bflo(vB.z), acc[4]); acc[5] = fmaf(wB, bfhi(vB.z), acc[5]);
    acc[6] = fmaf(wB, bflo(vB.w), acc[6]); acc[7] = fmaf(wB, bfhi(vB.w), acc[7]);
  }
#pragma unroll
  for (int t = 0; t < 2; ++t) {
    int idx = base + t * 4 + g;
    if (idx < nE) {
      int2 c0 = cw[e0 + idx];
      uint4 v = ((const uint4*)(feat + ((size_t)c0.x << 7)))[c16];
      float w0 = __int_as_float(c0.y);
      acc[0] = fmaf(w0, bflo(v.x), acc[0]); acc[1] = fmaf(w0, bfhi(v.x), acc[1]);
      acc[2] = fmaf(w0, bflo(v.y), acc[2]); acc[3] = fmaf(w0, bfhi(v.y), acc[3]);
      acc[4] = fmaf(w0, bflo(v.z), acc[4]); acc[5] = fmaf(w0, bfhi(v.z), acc[5]);
      acc[6] = fmaf(w0, bflo(v.w), acc[6]); acc[7] = fmaf(w0, bfhi(v.w), acc[7]);
    }
  }
#pragma unroll
  for (int j = 0; j < 8; ++j) {
    acc[j] += __shfl_xor(acc[j], 16);
    acc[j] += __shfl_xor(acc[j], 32);
  }
  {
    float sw = di * di;
    acc[0] = fmaf(sw, bflo(vSelf.x), acc[0]); acc[1] = fmaf(sw, bfhi(vSelf.x), acc[1]);
    acc[2] = fmaf(sw, bflo(vSelf.y), acc[2]); acc[3] = fmaf(sw, bfhi(vSelf.y), acc[3]);
    acc[4] = fmaf(sw, bflo(vSelf.z), acc[4]); acc[5] = fmaf(sw, bfhi(vSelf.z), acc[5]);
    acc[6] = fmaf(sw, bflo(vSelf.w), acc[6]); acc[7] = fmaf(sw, bfhi(vSelf.w), acc[7]);
  }
  int cOff = c16 * 8;
  float4 ba = *(const float4*)&b1[cOff];
  float4 bb = *(const float4*)&b1[cOff + 4];
  float a[8];
  a[0] = fmaxf(acc[0] + ba.x, 0.f); a[1] = fmaxf(acc[1] + ba.y, 0.f);
  a[2] = fmaxf(acc[2] + ba.z, 0.f); a[3] = fmaxf(acc[3] + ba.w, 0.f);
  a[4] = fmaxf(acc[4] + bb.x, 0.f); a[5] = fmaxf(acc[5] + bb.y, 0.f);
  a[6] = fmaxf(acc[6] + bb.z, 0.f); a[7] = fmaxf(acc[7] + bb.w, 0.f);
  float s = 0.f, sq = 0.f;
#pragma unroll
  for (int j = 0; j < 8; ++j) { s += a[j]; sq += a[j] * a[j]; }
#pragma unroll
  for (int m = 1; m < 16; m <<= 1) {
    s += __shfl_xor(s, m);
    sq += __shfl_xor(sq, m);
  }
  float mean = s * (1.f / 128.f);
  float var = sq * (1.f / 128.f) - mean * mean;
  float rstd = rsqrtf(var + EPSF);
  float4 ga = *(const float4*)&gamma[cOff];
  float4 gb = *(const float4*)&gamma[cOff + 4];
  float4 ea = *(const float4*)&beta[cOff];
  float4 eb = *(const float4*)&beta[cOff + 4];
  float o[8];
  o[0] = (a[0] - mean) * rstd * ga.x + ea.x; o[1] = (a[1] - mean) * rstd * ga.y + ea.y;
  o[2] = (a[2] - mean) * rstd * ga.z + ea.z; o[3] = (a[3] - mean) * rstd * ga.w + ea.w;
  o[4] = (a[4] - mean) * rstd * gb.x + eb.x; o[5] = (a[5] - mean) * rstd * gb.y + eb.y;
  o[6] = (a[6] - mean) * rstd * gb.z + eb.z; o[7] = (a[7] - mean) * rstd * gb.w + eb.w;
  if (g == 0) {
    uint4 p;
    p.x = pack2(o[0], o[1]); p.y = pack2(o[2], o[3]);
    p.z = pack2(o[4], o[5]); p.w = pack2(o[6], o[7]);
    ((uint4*)(outp + ((size_t)node << 7)))[c16] = p;
  }
}

// gather conv2+3 over hw, writes f32 [mu|logvar] directly with bias (nontemporal)
__global__ __launch_bounds__(256) void k_gather_out(const int* __restrict__ rowptr,
                                                    const int2* __restrict__ cw,
                                                    const float* __restrict__ dis,
                                                    const ushort* __restrict__ feat,
                                                    const float* __restrict__ bmu,
                                                    const float* __restrict__ blv,
                                                    float* __restrict__ out) {
  int node = blockIdx.x * 4 + (threadIdx.x >> 6);
  if (node >= NN) return;
  int l = threadIdx.x & 63;
  int g = l >> 4;
  int c16 = l & 15;

  float di = dis[node];
  uint4 vSelf = ((const uint4*)(feat + ((size_t)node << 7)))[c16];

  float acc[8] = {};
  int e0 = rowptr[node], nE = rowptr[node + 1] - e0;
  int base = 0;
  for (; base + 8 <= nE; base += 8) {
    int2 cA = cw[e0 + base + g];
    int2 cB = cw[e0 + base + 4 + g];
    uint4 vA = ((const uint4*)(feat + ((size_t)cA.x << 7)))[c16];
    uint4 vB = ((const uint4*)(feat + ((size_t)cB.x << 7)))[c16];
    float wA = __int_as_float(cA.y), wB = __int_as_float(cB.y);
    acc[0] = fmaf(wA, bflo(vA.x), acc[0]); acc[1] = fmaf(wA, bfhi(vA.x), acc[1]);
    acc[2] = fmaf(wA, bflo(vA.y), acc[2]); acc[3] = fmaf(wA, bfhi(vA.y), acc[3]);
    acc[4] = fmaf(wA, bflo(vA.z), acc[4]); acc[5] = fmaf(wA, bfhi(vA.z), acc[5]);
    acc[6] = fmaf(wA, bflo(vA.w), acc[6]); acc[7] = fmaf(wA, bfhi(vA.w), acc[7]);
    acc[0] = fmaf(wB, bflo(vB.x), acc[0]); acc[1] = fmaf(wB, bfhi(vB.x), acc[1]);
    acc[2] = fmaf(wB, bflo(vB.y), acc[2]); acc[3] = fmaf(wB, bfhi(vB.y), acc[3]);
    acc[4] = fmaf(wB, bflo(vB.z), acc[4]); acc[5] = fmaf(wB, bfhi(vB.z), acc[5]);
    acc[6] = fmaf(wB, bflo(vB.w), acc[6]); acc[7] = fmaf(wB, bfhi(vB.w), acc[7]);
  }
#pragma unroll
  for (int t = 0; t < 2; ++t) {
    int idx = base + t * 4 + g;
    if (idx < nE) {
      int2 c0 = cw[e0 + idx];
      uint4 v = ((const uint4*)(feat + ((size_t)c0.x << 7)))[c16];
      float w0 = __int_as_float(c0.y);
      acc[0] = fmaf(w0, bflo(v.x), acc[0]); acc[1] = fmaf(w0, bfhi(v.x), acc[1]);
      acc[2] = fmaf(w0, bflo(v.y), acc[2]); acc[3] = fmaf(w0, bfhi(v.y), acc[3]);
      acc[4] = fmaf(w0, bflo(v.z), acc[4]); acc[5] = fmaf(w0, bfhi(v.z), acc[5]);
      acc[6] = fmaf(w0, bflo(v.w), acc[6]); acc[7] = fmaf(w0, bfhi(v.w), acc[7]);
    }
  }
#pragma unroll
  for (int j = 0; j < 8; ++j) {
    acc[j] += __shfl_xor(acc[j], 16);
    acc[j] += __shfl_xor(acc[j], 32);
  }
  {
    float sw = di * di;
    acc[0] = fmaf(sw, bflo(vSelf.x), acc[0]); acc[1] = fmaf(sw, bfhi(vSelf.x), acc[1]);
    acc[2] = fmaf(sw, bflo(vSelf.y), acc[2]); acc[3] = fmaf(sw, bfhi(vSelf.y), acc[3]);
    acc[4] = fmaf(sw, bflo(vSelf.z), acc[4]); acc[5] = fmaf(sw, bfhi(vSelf.z), acc[5]);
    acc[6] = fmaf(sw, bflo(vSelf.w), acc[6]); acc[7] = fmaf(sw, bfhi(vSelf.w), acc[7]);
  }
  if (g == 0) {
    // feats c16*8..+8 of [mu(64) | logvar(64)]
    const float* bsrc = (c16 < 8) ? (bmu + c16 * 8) : (blv + (c16 - 8) * 8);
    float* osrc = (c16 < 8) ? (out + (size_t)node * OO + c16 * 8)
                            : (out + (size_t)NN * OO + (size_t)node * OO + (c16 - 8) * 8);
    float4 b0 = *(const float4*)bsrc;
    float4 b1 = *(const float4*)(bsrc + 4);
    floatx4 o0 = { acc[0] + b0.x, acc[1] + b0.y, acc[2] + b0.z, acc[3] + b0.w };
    floatx4 o1 = { acc[4] + b1.x, acc[5] + b1.y, acc[6] + b1.z, acc[7] + b1.w };
    __builtin_nontemporal_store(o0, (floatx4*)osrc);
    __builtin_nontemporal_store(o1, (floatx4*)(osrc + 4));
  }
}

extern "C" void kernel_launch(void* const* d_in, const int* in_sizes, int n_in,
                              void* d_out, int out_size, void* d_ws, size_t ws_size,
                              hipStream_t stream) {
  const float* x     = (const float*)d_in[0];
  const void*  ei    = d_in[1];
  const float* W1    = (const float*)d_in[2];
  const float* b1    = (const float*)d_in[3];
  const float* gamma = (const float*)d_in[4];
  const float* beta  = (const float*)d_in[5];
  const float* Wmu   = (const float*)d_in[6];
  const float* bmu   = (const float*)d_in[7];
  const float* Wlv   = (const float*)d_in[8];
  const float* blv   = (const float*)d_in[9];
  float* out = (float*)d_out;

  // workspace (4B words), ~72 MB:
  // [rowptr N+16][dis N][bsum 256][cnt N][histW NB*NW][boffW NB*NW]
  // [lrank E bytes][cw int2 E][t bf16][h bf16][hw bf16]
  int*   rowptr = (int*)d_ws;
  float* dis    = (float*)(rowptr + (NN + 16));
  int*   bsum   = (int*)(dis + NN);
  int*   cnt    = bsum + 256;                       // 16B-aligned (offset%4==0)
  uint*  histW  = (uint*)(cnt + NN);
  uint*  boffW  = histW + (size_t)NB * NW;
  uchar* lrank  = (uchar*)(boffW + (size_t)NB * NW);
  size_t off32  = (size_t)(NN + 16) + NN + 256 + NN + 2 * (size_t)NB * NW + EE / 4;
  off32 = (off32 + 63) & ~(size_t)63;
  int2*  cw     = (int2*)((int*)d_ws + off32);
  ushort* t  = (ushort*)(cw + EE);
  ushort* h  = t + (size_t)NN * FF;
  ushort* hw = h + (size_t)NN * FF;

  k_hist<<<NB, 512, 0, stream>>>(ei, histW, lrank);
  k_boff<<<(NW + 255) / 256, 256, 0, stream>>>(histW, boffW, cnt, dis, bsum);
  k_scan_all<<<SCB, 256, 0, stream>>>(cnt, bsum, rowptr);
  k_scatter_gemm1<<<GBLK + NB, 256, 0, stream>>>(ei, dis, rowptr, boffW,
                                                 lrank, cw, x, W1, t);

  k_gather_ln<<<(NN + 3) / 4, 256, 0, stream>>>(rowptr, cw, dis, t, b1, gamma, beta, h);
  k_gemmHW<<<GBLK, 256, 0, stream>>>(h, Wmu, Wlv, hw);
  k_gather_out<<<(NN + 3) / 4, 256, 0, stream>>>(rowptr, cw, dis, hw, bmu, blv, out);
}